// Round 9
// baseline (444.186 us; speedup 1.0000x reference)
//
#include <hip/hip_runtime.h>
#include <hip/hip_bf16.h>
#include <math.h>

typedef __attribute__((ext_vector_type(4))) float f4_t;
typedef __attribute__((ext_vector_type(8))) short s8_t;

constexpr int Bc = 64;      // batches
constexpr int Tc = 1024;    // tokens per batch (H*W)
constexpr int Cc = 512;     // channels
constexpr int Ec = 5;       // experts
constexpr int HIDc = 2048;  // hidden

// async global->LDS, 16B per lane (linear LDS dest: wave-uniform base + lane*16)
__device__ __forceinline__ void async_copy16(const void* gsrc, void* ldst) {
  __builtin_amdgcn_global_load_lds(
      (const __attribute__((address_space(1))) unsigned int*)gsrc,
      (__attribute__((address_space(3))) unsigned int*)ldst, 16, 0, 0);
}

// tanh-form gelu, folded. |err vs exact erf-gelu| ~ 2e-4 (<< bf16 rounding).
__device__ __forceinline__ float gelu_f(float v) {
  float v2 = v * v;
  float z = v * (1.5957691216f + 0.0713548162f * v2);
  float e = __expf(z);
  float r = __frcp_rn(1.0f + e);
  return v - v * r;
}

// ---------------- gating / prep ----------------

__global__ void k_prep(const float* __restrict__ x, ushort* __restrict__ xbf,
                       float* __restrict__ part) {
  int b = blockIdx.x, p = blockIdx.y, tid = threadIdx.x;
  const float4* xp = (const float4*)(x + ((size_t)b * Tc + (size_t)p * 128) * Cc);
  ushort4* op = (ushort4*)(xbf + ((size_t)b * Tc + (size_t)p * 128) * Cc);
  int c4 = tid & 127, r0 = tid >> 7;
  float4 s = {0.f, 0.f, 0.f, 0.f};
  for (int r = r0; r < 128; r += 2) {
    float4 v = xp[(size_t)r * 128 + c4];
    s.x += v.x; s.y += v.y; s.z += v.z; s.w += v.w;
    union { __hip_bfloat16 h[4]; ushort4 u; } cv;
    cv.h[0] = __float2bfloat16(v.x);
    cv.h[1] = __float2bfloat16(v.y);
    cv.h[2] = __float2bfloat16(v.z);
    cv.h[3] = __float2bfloat16(v.w);
    op[(size_t)r * 128 + c4] = cv.u;
  }
  __shared__ float4 sh[128];
  if (r0) sh[c4] = s;
  __syncthreads();
  if (!r0) {
    float4 o = sh[c4];
    s.x += o.x; s.y += o.y; s.z += o.z; s.w += o.w;
    ((float4*)part)[(size_t)(b * 8 + p) * 128 + c4] = s;
  }
}

__global__ void k_partial(const float* __restrict__ x, float* __restrict__ part) {
  int b = blockIdx.x, p = blockIdx.y, tid = threadIdx.x;
  const float* xp = x + ((size_t)b * Tc + (size_t)p * 128) * Cc;
  float s0 = 0.f, s1 = 0.f;
  for (int t = 0; t < 128; ++t) {
    s0 += xp[(size_t)t * Cc + tid];
    s1 += xp[(size_t)t * Cc + tid + 256];
  }
  part[(size_t)(b * 8 + p) * Cc + tid] = s0;
  part[(size_t)(b * 8 + p) * Cc + tid + 256] = s1;
}

__global__ void k_cvt_x(const float* __restrict__ src, ushort* __restrict__ dst, int n4) {
  int i = blockIdx.x * blockDim.x + threadIdx.x;
  int stride = gridDim.x * blockDim.x;
  const float4* s4 = (const float4*)src;
  ushort4* d4 = (ushort4*)dst;
  for (; i < n4; i += stride) {
    float4 v = s4[i];
    union { __hip_bfloat16 h[4]; ushort4 u; } cv;
    cv.h[0] = __float2bfloat16(v.x);
    cv.h[1] = __float2bfloat16(v.y);
    cv.h[2] = __float2bfloat16(v.z);
    cv.h[3] = __float2bfloat16(v.w);
    d4[i] = cv.u;
  }
}

__global__ void k_xg_logits(const float* __restrict__ part, const float* __restrict__ wg,
                            float* __restrict__ logits) {
  __shared__ float xg[Cc];
  __shared__ float red[Ec][4];
  int b = blockIdx.x, tid = threadIdx.x;
  for (int c = tid; c < Cc; c += 256) {
    float s = 0.f;
#pragma unroll
    for (int p = 0; p < 8; ++p) s += part[(size_t)(b * 8 + p) * Cc + c];
    xg[c] = s * (1.0f / 1024.0f);
  }
  __syncthreads();
  float le[Ec] = {0.f, 0.f, 0.f, 0.f, 0.f};
  for (int c = tid; c < Cc; c += 256) {
    float v = xg[c];
#pragma unroll
    for (int e = 0; e < Ec; ++e) le[e] += v * wg[c * Ec + e];
  }
#pragma unroll
  for (int e = 0; e < Ec; ++e) {
    float v = le[e];
#pragma unroll
    for (int off = 32; off > 0; off >>= 1) v += __shfl_down(v, off);
    if ((tid & 63) == 0) red[e][tid >> 6] = v;
  }
  __syncthreads();
  if (tid < Ec) {
    float v = red[tid][0] + red[tid][1] + red[tid][2] + red[tid][3];
    v = fminf(fmaxf(v, -50.f), 50.f);
    logits[b * Ec + tid] = v;
  }
}

__global__ void k_gate(const float* __restrict__ logits, int* __restrict__ idx,
                       float* __restrict__ loss_out) {
  __shared__ int cnt[Ec];
  int tid = threadIdx.x;
  if (tid < Ec) cnt[tid] = 0;
  __syncthreads();
  if (tid < Bc) {
    const float* lb = logits + tid * Ec;
    int best = 0;
    float bv = lb[0];
#pragma unroll
    for (int e = 1; e < Ec; ++e) {
      float v = lb[e];
      if (v > bv) { bv = v; best = e; }
    }
    idx[tid] = best;
    atomicAdd(&cnt[best], 1);
  }
  __syncthreads();
  if (tid == 0) {
    const float mean = (float)Bc / (float)Ec;
    float var = 0.f;
#pragma unroll
    for (int e = 0; e < Ec; ++e) {
      float d = (float)cnt[e] - mean;
      var += d * d;
    }
    var *= (1.0f / (Ec - 1));
    float loss = 2.f * (var / (mean * mean + 1e-10f));
    loss = fminf(fmaxf(loss, 0.f), 1000.f);
    *loss_out = loss;
  }
}

__global__ void k_transpose_cvt(const float* __restrict__ src, __hip_bfloat16* __restrict__ dst,
                                int K, int N) {
  __shared__ float tile[32][33];
  int e = blockIdx.z;
  int kb = blockIdx.y * 32, nb = blockIdx.x * 32;
  const float* s = src + (size_t)e * K * N;
  __hip_bfloat16* d = dst + (size_t)e * K * N;
  int lx = threadIdx.x & 31, ly = threadIdx.x >> 5;
#pragma unroll
  for (int r = 0; r < 4; ++r) {
    int k = kb + ly + r * 8;
    tile[ly + r * 8][lx] = s[(size_t)k * N + nb + lx];
  }
  __syncthreads();
#pragma unroll
  for (int r = 0; r < 4; ++r) {
    int n = nb + ly + r * 8;
    d[(size_t)n * K + kb + lx] = __float2bfloat16(tile[lx][ly + r * 8]);
  }
}

// =====================================================================
// 8-phase schedule on 256x256/BK=64/8-wave, dbuf LDS, T2 swizzle, T5
// setprio, counted vmcnt(4) once per K-tile (never 0 mid-loop).
// Per-phase lgkmcnt handled by the COMPILER (reads are C-level; partial
// waits allow read/MFMA interleave).  WAR safety: each fragment read's
// compiler wait precedes its consuming MFMA, which precedes the phase's
// closing barrier, which precedes any overwriting stage issue (vmcnt
// asm-clobbers pin memory order).
// gemm1 additionally runs TWO M-panels per block (seamless: KLOOP8 ->
// epilogue -> warm re-prologue -> KLOOP8) to halve block-round dead time.
// =====================================================================

#define GEMM_PRELUDE(KDIM)                                               \
  int tid = threadIdx.x, l = tid & 63, w = tid >> 6;                     \
  int wr = w >> 2, wc = w & 3;                                           \
  const short* gA[4];                                                    \
  const short* gB[4];                                                    \
  int loff[4];                                                           \
  _Pragma("unroll")                                                      \
  for (int i = 0; i < 4; ++i) {                                          \
    int sp = i * 512 + tid;                                              \
    int r = sp >> 3;                                                     \
    int c8 = ((sp & 7) ^ (r & 7)) << 3;                                  \
    gA[i] = Ab + (size_t)r * (KDIM) + c8;                                \
    gB[i] = Bb + (size_t)r * (KDIM) + c8;                                \
    loff[i] = sp * 16;                                                   \
  }                                                                      \
  int abase = (wr * 128 + (l & 15)) * 128;                               \
  int bbase = (wc * 64 + (l & 15)) * 128;                                \
  int s0 = (((l >> 4)) ^ (l & 7)) << 4;                                  \
  int s1 = (((l >> 4) + 4) ^ (l & 7)) << 4;

#define STAGE_A_HALF(buf, h, kt)                                         \
  {                                                                      \
    char* d_ = (char*)&lds[buf][0][0];                                   \
    int k0_ = (kt) * 64;                                                 \
    async_copy16(gA[2 * (h)] + k0_, d_ + loff[2 * (h)]);                 \
    async_copy16(gA[2 * (h) + 1] + k0_, d_ + loff[2 * (h) + 1]);         \
  }
#define STAGE_B_HALF(buf, h, kt)                                         \
  {                                                                      \
    char* d_ = (char*)&lds[buf][1][0];                                   \
    int k0_ = (kt) * 64;                                                 \
    async_copy16(gB[2 * (h)] + k0_, d_ + loff[2 * (h)]);                 \
    async_copy16(gB[2 * (h) + 1] + k0_, d_ + loff[2 * (h) + 1]);         \
  }

// one phase: q = quad index (0..3)
#define PH8(q, tt, NTv)                                                      \
  {                                                                          \
    const char* As_ = (const char*)&lds[(tt) & 1][0][0];                     \
    const char* Bs_ = (const char*)&lds[(tt) & 1][1][0];                     \
    if ((q) == 0) {                                                          \
      _Pragma("unroll")                                                      \
      for (int fn = 0; fn < 4; ++fn) {                                       \
        bfr[fn * 2 + 0] = *(const s8_t*)(Bs_ + bbase + fn * 2048 + s0);      \
        bfr[fn * 2 + 1] = *(const s8_t*)(Bs_ + bbase + fn * 2048 + s1);      \
      }                                                                      \
    }                                                                        \
    afr[0] = *(const s8_t*)(As_ + abase + ((q) * 2 + 0) * 2048 + s0);        \
    afr[1] = *(const s8_t*)(As_ + abase + ((q) * 2 + 0) * 2048 + s1);        \
    afr[2] = *(const s8_t*)(As_ + abase + ((q) * 2 + 1) * 2048 + s0);        \
    afr[3] = *(const s8_t*)(As_ + abase + ((q) * 2 + 1) * 2048 + s1);        \
    if ((q) == 0 && (tt) + 1 < (NTv)) STAGE_A_HALF(((tt) + 1) & 1, 0, (tt) + 1) \
    if ((q) == 1 && (tt) + 1 < (NTv)) STAGE_A_HALF(((tt) + 1) & 1, 1, (tt) + 1) \
    if ((q) == 2 && (tt) + 2 < (NTv)) STAGE_B_HALF((tt) & 1, 0, (tt) + 2)    \
    if ((q) == 3 && (tt) + 2 < (NTv)) STAGE_B_HALF((tt) & 1, 1, (tt) + 2)    \
    __builtin_amdgcn_s_barrier();                                            \
    asm volatile("" ::: "memory");                                           \
    __builtin_amdgcn_s_setprio(1);                                           \
    _Pragma("unroll")                                                        \
    for (int kk = 0; kk < 2; ++kk)                                           \
      _Pragma("unroll")                                                      \
      for (int j = 0; j < 2; ++j)                                            \
        _Pragma("unroll")                                                    \
        for (int fn = 0; fn < 4; ++fn)                                       \
          acc[(q) * 2 + j][fn] = __builtin_amdgcn_mfma_f32_16x16x32_bf16(    \
              afr[j * 2 + kk], bfr[fn * 2 + kk], acc[(q) * 2 + j][fn], 0, 0, 0); \
    __builtin_amdgcn_s_setprio(0);                                           \
    if ((q) == 3) {                                                          \
      if ((tt) + 2 < (NTv)) {                                                \
        asm volatile("s_waitcnt vmcnt(4)" ::: "memory");                     \
      } else if ((tt) + 1 < (NTv)) {                                         \
        asm volatile("s_waitcnt vmcnt(0)" ::: "memory");                     \
      }                                                                      \
    }                                                                        \
    __builtin_amdgcn_s_barrier();                                            \
    asm volatile("" ::: "memory");                                           \
  }

#define KLOOP8(NTv)                                                      \
  s8_t bfr[8], afr[4];                                                   \
  STAGE_B_HALF(0, 0, 0)                                                  \
  STAGE_B_HALF(0, 1, 0)                                                  \
  STAGE_A_HALF(0, 0, 0)                                                  \
  STAGE_A_HALF(0, 1, 0)                                                  \
  STAGE_B_HALF(1, 0, 1)                                                  \
  STAGE_B_HALF(1, 1, 1)                                                  \
  asm volatile("s_waitcnt vmcnt(4)" ::: "memory");                       \
  __builtin_amdgcn_s_barrier();                                          \
  asm volatile("" ::: "memory");                                         \
  _Pragma("unroll 2")                                                    \
  for (int t = 0; t < (NTv); ++t) {                                      \
    PH8(0, t, NTv)                                                       \
    PH8(1, t, NTv)                                                       \
    PH8(2, t, NTv)                                                       \
    PH8(3, t, NTv)                                                       \
  }

// GEMM1: h = gelu(x @ W1[e] + b1[e]); A xbf [cb][1024][512], B w1t [E][2048][512]
// TWO 256-row M-panels per block (grid = 8 * 2 * cb).
__global__ __launch_bounds__(512, 2) void k_gemm1(
    const __hip_bfloat16* __restrict__ xbf, const __hip_bfloat16* __restrict__ w1t,
    const float* __restrict__ b1, const int* __restrict__ idx, int b0, int nz,
    __hip_bfloat16* __restrict__ h) {
  constexpr int K = Cc;       // 512
  constexpr int N = HIDc;     // 2048
  constexpr int NT = K / 64;  // 8
  constexpr int NBX = N / 256, NBY = Tc / 512;  // 8, 2
  __shared__ short lds[2][2][256 * 64];  // 128 KB

  int nwg = NBX * NBY * nz;  // 16*nz, %8==0
  int cpx = nwg >> 3;
  int lg = (blockIdx.x & 7) * cpx + (blockIdx.x >> 3);
  int bx = lg % NBX, by = (lg / NBX) % NBY, bz = lg / (NBX * NBY);

  int e = idx[b0 + bz];
  int n0 = bx * 256;
  const short* Ab = (const short*)xbf + ((size_t)bz * Tc + by * 512) * K;
  const short* Bb = (const short*)w1t + ((size_t)e * N + n0) * K;

  GEMM_PRELUDE(K)
  f4_t acc[8][4] = {};
  short* hb = (short*)(h + (size_t)bz * Tc * N);
  const float* bias = b1 + (size_t)e * N;
  int cc2 = (l & 7) * 8;

#pragma unroll 1
  for (int panel = 0; panel < 2; ++panel) {
    if (panel) {
#pragma unroll
      for (int i = 0; i < 4; ++i) gA[i] += (size_t)256 * K;
      __syncthreads();  // epilogue scratch WAR before restaging
    }
    { KLOOP8(NT) }

    // epilogue: bias+gelu -> two-pass per-wave LDS transpose (stride 72)
    __syncthreads();
    int m0 = by * 512 + panel * 256;
    short* chunk = &lds[0][0][0] + w * (64 * 72);  // 9216 B per wave
#pragma unroll
    for (int p = 0; p < 2; ++p) {
#pragma unroll
      for (int fn = 0; fn < 4; ++fn) {
        float bv = bias[n0 + wc * 64 + fn * 16 + (l & 15)];
#pragma unroll
        for (int fm = 0; fm < 4; ++fm) {
          int rl = fm * 16 + ((l >> 4) << 2);
#pragma unroll
          for (int j = 0; j < 4; ++j) {
            float v = gelu_f(acc[p * 4 + fm][fn][j] + bv);
            chunk[(rl + j) * 72 + fn * 16 + (l & 15)] =
                (short)__bfloat16_as_ushort(__float2bfloat16(v));
          }
        }
      }
#pragma unroll
      for (int q = 0; q < 8; ++q) {
        int rr = q * 8 + (l >> 3);
        s8_t v = *(const s8_t*)(chunk + rr * 72 + cc2);
        *(s8_t*)(hb + (size_t)(m0 + wr * 128 + p * 64 + rr) * N + n0 + wc * 64 + cc2) = v;
      }
      // WAR fence: pass-1 LDS writes must not pass pass-0 reads
      asm volatile("s_waitcnt lgkmcnt(0)" ::: "memory");
    }
    // reset accumulator for next panel
#pragma unroll
    for (int fm = 0; fm < 8; ++fm)
#pragma unroll
      for (int fn = 0; fn < 4; ++fn) acc[fm][fn] = (f4_t){0.f, 0.f, 0.f, 0.f};
  }
}

// GEMM2: y = h @ W2[e] + b2[e]; A h [cb][1024][2048], B w2t [E][512][2048]
__global__ __launch_bounds__(512, 2) void k_gemm2(
    const __hip_bfloat16* __restrict__ h, const __hip_bfloat16* __restrict__ w2t,
    const float* __restrict__ b2, const int* __restrict__ idx, int b0, int nz,
    float* __restrict__ out) {
  constexpr int K = HIDc;     // 2048
  constexpr int N = Cc;       // 512
  constexpr int NT = K / 64;  // 32
  constexpr int NBX = N / 256, NBY = Tc / 256;  // 2, 4
  __shared__ short lds[2][2][256 * 64];  // 128 KB

  int nwg = NBX * NBY * nz;  // 8*nz
  int cpx = nwg >> 3;
  int lg = (blockIdx.x & 7) * cpx + (blockIdx.x >> 3);
  int bx = lg % NBX, by = (lg / NBX) % NBY, bz = lg / (NBX * NBY);

  int e = idx[b0 + bz];
  int m0 = by * 256, n0 = bx * 256;
  const short* Ab = (const short*)h + ((size_t)bz * Tc + m0) * K;
  const short* Bb = (const short*)w2t + ((size_t)e * N + n0) * K;

  GEMM_PRELUDE(K)
  f4_t acc[8][4] = {};
  { KLOOP8(NT) }

  float* ob = out + (size_t)(b0 + bz) * Tc * N;
  const float* bias = b2 + (size_t)e * N;
#pragma unroll
  for (int fn = 0; fn < 4; ++fn) {
    int col = n0 + wc * 64 + fn * 16 + (l & 15);
    float bv = bias[col];
#pragma unroll
    for (int fm = 0; fm < 8; ++fm) {
      int rbase = m0 + wr * 128 + fm * 16 + ((l >> 4) << 2);
#pragma unroll
      for (int j = 0; j < 4; ++j) {
        ob[(size_t)(rbase + j) * N + col] = acc[fm][fn][j] + bv;
      }
    }
  }
}

extern "C" void kernel_launch(void* const* d_in, const int* in_sizes, int n_in,
                              void* d_out, int out_size, void* d_ws, size_t ws_size,
                              hipStream_t stream) {
  const float* x  = (const float*)d_in[0];
  const float* wg = (const float*)d_in[1];
  const float* W1 = (const float*)d_in[2];
  const float* b1 = (const float*)d_in[3];
  const float* W2 = (const float*)d_in[4];
  const float* b2 = (const float*)d_in[5];
  float* out = (float*)d_out;

  char* ws = (char*)d_ws;
  size_t off = 0;
  float* part = (float*)(ws + off); off += (size_t)Bc * 8 * Cc * 4;
  float* logits = (float*)(ws + off); off += (size_t)Bc * Ec * 4;
  int* idx = (int*)(ws + off); off += (size_t)Bc * 4;
  off = (off + 255) & ~(size_t)255;
  __hip_bfloat16* w1t = (__hip_bfloat16*)(ws + off); off += (size_t)Ec * HIDc * Cc * 2;
  __hip_bfloat16* w2t = (__hip_bfloat16*)(ws + off); off += (size_t)Ec * HIDc * Cc * 2;
  size_t dynoff = (off + 255) & ~(size_t)255;

  const size_t x_all = (size_t)Bc * Tc * Cc * 2;   // 64 MB
  const size_t x_per_b = (size_t)Tc * Cc * 2;      // 1 MB
  const size_t h_per_b = (size_t)Tc * HIDc * 2;    // 4 MB

  k_transpose_cvt<<<dim3(HIDc / 32, Cc / 32, Ec), 256, 0, stream>>>(W1, w1t, Cc, HIDc);
  k_transpose_cvt<<<dim3(Cc / 32, HIDc / 32, Ec), 256, 0, stream>>>(W2, w2t, HIDc, Cc);

  if (ws_size >= dynoff + x_all + h_per_b) {
    __hip_bfloat16* xbf = (__hip_bfloat16*)(ws + dynoff);
    __hip_bfloat16* hbf = (__hip_bfloat16*)(ws + dynoff + x_all);
    int cb = (int)((ws_size - dynoff - x_all) / h_per_b);
    if (cb > 32) cb = 32;  // h chunk <=128MB: L3-resident between gemm1/gemm2

    k_prep<<<dim3(Bc, 8), 256, 0, stream>>>(x, (ushort*)xbf, part);
    k_xg_logits<<<dim3(Bc), 256, 0, stream>>>(part, wg, logits);
    k_gate<<<dim3(1), 256, 0, stream>>>(logits, idx, out + ((size_t)out_size - 1));

    for (int b0 = 0; b0 < Bc; b0 += cb) {
      int c = (Bc - b0) < cb ? (Bc - b0) : cb;
      const __hip_bfloat16* xc = xbf + (size_t)b0 * Tc * Cc;
      k_gemm1<<<dim3((HIDc / 256) * (Tc / 512) * c), 512, 0, stream>>>(
          xc, w1t, b1, idx, b0, c, hbf);
      k_gemm2<<<dim3((Cc / 256) * (Tc / 256) * c), 512, 0, stream>>>(
          hbf, w2t, b2, idx, b0, c, out);
    }
  } else {
    size_t avail = ws_size > dynoff ? ws_size - dynoff : 0;
    int cb = (int)(avail / (x_per_b + h_per_b));
    if (cb > 32) cb = 32;
    if (cb < 1) cb = 1;
    __hip_bfloat16* xbf = (__hip_bfloat16*)(ws + dynoff);
    __hip_bfloat16* hbf = (__hip_bfloat16*)(ws + dynoff + (size_t)cb * x_per_b);

    k_partial<<<dim3(Bc, 8), 256, 0, stream>>>(x, part);
    k_xg_logits<<<dim3(Bc), 256, 0, stream>>>(part, wg, logits);
    k_gate<<<dim3(1), 256, 0, stream>>>(logits, idx, out + ((size_t)out_size - 1));

    for (int b0 = 0; b0 < Bc; b0 += cb) {
      int c = (Bc - b0) < cb ? (Bc - b0) : cb;
      int n4 = c * (Tc * Cc / 4);
      k_cvt_x<<<dim3(1024), 256, 0, stream>>>(x + (size_t)b0 * Tc * Cc, (ushort*)xbf, n4);
      k_gemm1<<<dim3((HIDc / 256) * (Tc / 512) * c), 512, 0, stream>>>(
          xbf, w1t, b1, idx, b0, c, hbf);
      k_gemm2<<<dim3((Cc / 256) * (Tc / 256) * c), 512, 0, stream>>>(
          hbf, w2t, b2, idx, b0, c, out);
    }
  }
}

// Round 10
// 437.978 us; speedup vs baseline: 1.0142x; 1.0142x over previous
//
#include <hip/hip_runtime.h>
#include <hip/hip_bf16.h>
#include <math.h>

typedef __attribute__((ext_vector_type(4))) float f4_t;
typedef __attribute__((ext_vector_type(8))) short s8_t;

constexpr int Bc = 64;      // batches
constexpr int Tc = 1024;    // tokens per batch (H*W)
constexpr int Cc = 512;     // channels
constexpr int Ec = 5;       // experts
constexpr int HIDc = 2048;  // hidden

// async global->LDS, 16B per lane (linear LDS dest: wave-uniform base + lane*16)
__device__ __forceinline__ void async_copy16(const void* gsrc, void* ldst) {
  __builtin_amdgcn_global_load_lds(
      (const __attribute__((address_space(1))) unsigned int*)gsrc,
      (__attribute__((address_space(3))) unsigned int*)ldst, 16, 0, 0);
}

// tanh-form gelu, folded. |err vs exact erf-gelu| ~ 2e-4 (<< bf16 rounding).
__device__ __forceinline__ float gelu_f(float v) {
  float v2 = v * v;
  float z = v * (1.5957691216f + 0.0713548162f * v2);
  float e = __expf(z);
  float r = __frcp_rn(1.0f + e);
  return v - v * r;
}

// ---------------- gating / prep ----------------

__global__ void k_prep(const float* __restrict__ x, ushort* __restrict__ xbf,
                       float* __restrict__ part) {
  int b = blockIdx.x, p = blockIdx.y, tid = threadIdx.x;
  const float4* xp = (const float4*)(x + ((size_t)b * Tc + (size_t)p * 128) * Cc);
  ushort4* op = (ushort4*)(xbf + ((size_t)b * Tc + (size_t)p * 128) * Cc);
  int c4 = tid & 127, r0 = tid >> 7;
  float4 s = {0.f, 0.f, 0.f, 0.f};
  for (int r = r0; r < 128; r += 2) {
    float4 v = xp[(size_t)r * 128 + c4];
    s.x += v.x; s.y += v.y; s.z += v.z; s.w += v.w;
    union { __hip_bfloat16 h[4]; ushort4 u; } cv;
    cv.h[0] = __float2bfloat16(v.x);
    cv.h[1] = __float2bfloat16(v.y);
    cv.h[2] = __float2bfloat16(v.z);
    cv.h[3] = __float2bfloat16(v.w);
    op[(size_t)r * 128 + c4] = cv.u;
  }
  __shared__ float4 sh[128];
  if (r0) sh[c4] = s;
  __syncthreads();
  if (!r0) {
    float4 o = sh[c4];
    s.x += o.x; s.y += o.y; s.z += o.z; s.w += o.w;
    ((float4*)part)[(size_t)(b * 8 + p) * 128 + c4] = s;
  }
}

__global__ void k_partial(const float* __restrict__ x, float* __restrict__ part) {
  int b = blockIdx.x, p = blockIdx.y, tid = threadIdx.x;
  const float* xp = x + ((size_t)b * Tc + (size_t)p * 128) * Cc;
  float s0 = 0.f, s1 = 0.f;
  for (int t = 0; t < 128; ++t) {
    s0 += xp[(size_t)t * Cc + tid];
    s1 += xp[(size_t)t * Cc + tid + 256];
  }
  part[(size_t)(b * 8 + p) * Cc + tid] = s0;
  part[(size_t)(b * 8 + p) * Cc + tid + 256] = s1;
}

__global__ void k_cvt_x(const float* __restrict__ src, ushort* __restrict__ dst, int n4) {
  int i = blockIdx.x * blockDim.x + threadIdx.x;
  int stride = gridDim.x * blockDim.x;
  const float4* s4 = (const float4*)src;
  ushort4* d4 = (ushort4*)dst;
  for (; i < n4; i += stride) {
    float4 v = s4[i];
    union { __hip_bfloat16 h[4]; ushort4 u; } cv;
    cv.h[0] = __float2bfloat16(v.x);
    cv.h[1] = __float2bfloat16(v.y);
    cv.h[2] = __float2bfloat16(v.z);
    cv.h[3] = __float2bfloat16(v.w);
    d4[i] = cv.u;
  }
}

__global__ void k_xg_logits(const float* __restrict__ part, const float* __restrict__ wg,
                            float* __restrict__ logits) {
  __shared__ float xg[Cc];
  __shared__ float red[Ec][4];
  int b = blockIdx.x, tid = threadIdx.x;
  for (int c = tid; c < Cc; c += 256) {
    float s = 0.f;
#pragma unroll
    for (int p = 0; p < 8; ++p) s += part[(size_t)(b * 8 + p) * Cc + c];
    xg[c] = s * (1.0f / 1024.0f);
  }
  __syncthreads();
  float le[Ec] = {0.f, 0.f, 0.f, 0.f, 0.f};
  for (int c = tid; c < Cc; c += 256) {
    float v = xg[c];
#pragma unroll
    for (int e = 0; e < Ec; ++e) le[e] += v * wg[c * Ec + e];
  }
#pragma unroll
  for (int e = 0; e < Ec; ++e) {
    float v = le[e];
#pragma unroll
    for (int off = 32; off > 0; off >>= 1) v += __shfl_down(v, off);
    if ((tid & 63) == 0) red[e][tid >> 6] = v;
  }
  __syncthreads();
  if (tid < Ec) {
    float v = red[tid][0] + red[tid][1] + red[tid][2] + red[tid][3];
    v = fminf(fmaxf(v, -50.f), 50.f);
    logits[b * Ec + tid] = v;
  }
}

__global__ void k_gate(const float* __restrict__ logits, int* __restrict__ idx,
                       float* __restrict__ loss_out) {
  __shared__ int cnt[Ec];
  int tid = threadIdx.x;
  if (tid < Ec) cnt[tid] = 0;
  __syncthreads();
  if (tid < Bc) {
    const float* lb = logits + tid * Ec;
    int best = 0;
    float bv = lb[0];
#pragma unroll
    for (int e = 1; e < Ec; ++e) {
      float v = lb[e];
      if (v > bv) { bv = v; best = e; }
    }
    idx[tid] = best;
    atomicAdd(&cnt[best], 1);
  }
  __syncthreads();
  if (tid == 0) {
    const float mean = (float)Bc / (float)Ec;
    float var = 0.f;
#pragma unroll
    for (int e = 0; e < Ec; ++e) {
      float d = (float)cnt[e] - mean;
      var += d * d;
    }
    var *= (1.0f / (Ec - 1));
    float loss = 2.f * (var / (mean * mean + 1e-10f));
    loss = fminf(fmaxf(loss, 0.f), 1000.f);
    *loss_out = loss;
  }
}

__global__ void k_transpose_cvt(const float* __restrict__ src, __hip_bfloat16* __restrict__ dst,
                                int K, int N) {
  __shared__ float tile[32][33];
  int e = blockIdx.z;
  int kb = blockIdx.y * 32, nb = blockIdx.x * 32;
  const float* s = src + (size_t)e * K * N;
  __hip_bfloat16* d = dst + (size_t)e * K * N;
  int lx = threadIdx.x & 31, ly = threadIdx.x >> 5;
#pragma unroll
  for (int r = 0; r < 4; ++r) {
    int k = kb + ly + r * 8;
    tile[ly + r * 8][lx] = s[(size_t)k * N + nb + lx];
  }
  __syncthreads();
#pragma unroll
  for (int r = 0; r < 4; ++r) {
    int n = nb + ly + r * 8;
    d[(size_t)n * K + kb + lx] = __float2bfloat16(tile[lx][ly + r * 8]);
  }
}

// =====================================================================
// Pipelined 4-phase schedule, 256x256/BK=64/8-wave, dbuf LDS, T2 swizzle,
// T5 setprio, counted vmcnt(4).  NEW: reads are software-pipelined one
// phase ahead -> each phase = { MFMA(q) [regs read last phase] ; stage
// half ; read quad q+1 (issues UNDER the executing MFMAs) ; barrier }.
// One barrier per phase (4/tile).  Cross-tile pre-read (bfr + quad0 of
// buf^1) sits AFTER the q3 counted vmcnt(4) (which drains A(t+1)+B(t+1),
// leaving only B(t+2) in flight) and is fenced by lgkmcnt(0) before the
// q3 barrier so a fast wave's next-tile A-stage cannot land under a slow
// wave's pending reads.  acc quads are disjoint per phase -> no MFMA
// dependency stalls; same-acc reuse is 4 phases apart.
// =====================================================================

#define GEMM_PRELUDE(KDIM)                                               \
  int tid = threadIdx.x, l = tid & 63, w = tid >> 6;                     \
  int wr = w >> 2, wc = w & 3;                                           \
  const short* gA[4];                                                    \
  const short* gB[4];                                                    \
  int loff[4];                                                           \
  _Pragma("unroll")                                                      \
  for (int i = 0; i < 4; ++i) {                                          \
    int sp = i * 512 + tid;                                              \
    int r = sp >> 3;                                                     \
    int c8 = ((sp & 7) ^ (r & 7)) << 3;                                  \
    gA[i] = Ab + (size_t)r * (KDIM) + c8;                                \
    gB[i] = Bb + (size_t)r * (KDIM) + c8;                                \
    loff[i] = sp * 16;                                                   \
  }                                                                      \
  int abase = (wr * 128 + (l & 15)) * 128;                               \
  int bbase = (wc * 64 + (l & 15)) * 128;                                \
  int s0 = (((l >> 4)) ^ (l & 7)) << 4;                                  \
  int s1 = (((l >> 4) + 4) ^ (l & 7)) << 4;

#define STAGE_A_HALF(buf, h, kt)                                         \
  {                                                                      \
    char* d_ = (char*)&lds[buf][0][0];                                   \
    int k0_ = (kt) * 64;                                                 \
    async_copy16(gA[2 * (h)] + k0_, d_ + loff[2 * (h)]);                 \
    async_copy16(gA[2 * (h) + 1] + k0_, d_ + loff[2 * (h) + 1]);         \
  }
#define STAGE_B_HALF(buf, h, kt)                                         \
  {                                                                      \
    char* d_ = (char*)&lds[buf][1][0];                                   \
    int k0_ = (kt) * 64;                                                 \
    async_copy16(gB[2 * (h)] + k0_, d_ + loff[2 * (h)]);                 \
    async_copy16(gB[2 * (h) + 1] + k0_, d_ + loff[2 * (h) + 1]);         \
  }

#define READ_QUAD(AFR, bufp, qq)                                         \
  {                                                                      \
    const char* Aq_ = (const char*)&lds[bufp][0][0];                     \
    AFR[0] = *(const s8_t*)(Aq_ + abase + ((qq) * 2 + 0) * 2048 + s0);   \
    AFR[1] = *(const s8_t*)(Aq_ + abase + ((qq) * 2 + 0) * 2048 + s1);   \
    AFR[2] = *(const s8_t*)(Aq_ + abase + ((qq) * 2 + 1) * 2048 + s0);   \
    AFR[3] = *(const s8_t*)(Aq_ + abase + ((qq) * 2 + 1) * 2048 + s1);   \
  }

#define READ_BFR(bufp)                                                   \
  {                                                                      \
    const char* Bq_ = (const char*)&lds[bufp][1][0];                     \
    _Pragma("unroll")                                                    \
    for (int fn = 0; fn < 4; ++fn) {                                     \
      bfr[fn * 2 + 0] = *(const s8_t*)(Bq_ + bbase + fn * 2048 + s0);    \
      bfr[fn * 2 + 1] = *(const s8_t*)(Bq_ + bbase + fn * 2048 + s1);    \
    }                                                                    \
  }

#define PH_PIPE(q, tt, NTv, ACUR, ANXT)                                      \
  {                                                                          \
    __builtin_amdgcn_s_setprio(1);                                           \
    _Pragma("unroll")                                                        \
    for (int kk = 0; kk < 2; ++kk)                                           \
      _Pragma("unroll")                                                      \
      for (int j = 0; j < 2; ++j)                                            \
        _Pragma("unroll")                                                    \
        for (int fn = 0; fn < 4; ++fn)                                       \
          acc[(q) * 2 + j][fn] = __builtin_amdgcn_mfma_f32_16x16x32_bf16(    \
              ACUR[j * 2 + kk], bfr[fn * 2 + kk], acc[(q) * 2 + j][fn], 0, 0, 0); \
    __builtin_amdgcn_s_setprio(0);                                           \
    if ((q) == 0 && (tt) + 1 < (NTv)) STAGE_A_HALF(((tt) + 1) & 1, 0, (tt) + 1) \
    if ((q) == 1 && (tt) + 1 < (NTv)) STAGE_A_HALF(((tt) + 1) & 1, 1, (tt) + 1) \
    if ((q) == 2 && (tt) + 2 < (NTv)) STAGE_B_HALF((tt) & 1, 0, (tt) + 2)    \
    if ((q) == 3 && (tt) + 2 < (NTv)) STAGE_B_HALF((tt) & 1, 1, (tt) + 2)    \
    if ((q) < 3) {                                                           \
      READ_QUAD(ANXT, (tt) & 1, (q) + 1)                                     \
    } else {                                                                 \
      if ((tt) + 2 < (NTv)) {                                                \
        asm volatile("s_waitcnt vmcnt(4)" ::: "memory");                     \
      } else if ((tt) + 1 < (NTv)) {                                         \
        asm volatile("s_waitcnt vmcnt(0)" ::: "memory");                     \
      }                                                                      \
      if ((tt) + 1 < (NTv)) {                                                \
        READ_BFR(((tt) + 1) & 1)                                             \
        READ_QUAD(ANXT, ((tt) + 1) & 1, 0)                                   \
        asm volatile("s_waitcnt lgkmcnt(0)" ::: "memory");                   \
      }                                                                      \
    }                                                                        \
    __builtin_amdgcn_s_barrier();                                            \
    asm volatile("" ::: "memory");                                           \
  }

#define KLOOP8(NTv)                                                      \
  s8_t bfr[8], afrA[4], afrB[4];                                         \
  STAGE_B_HALF(0, 0, 0)                                                  \
  STAGE_B_HALF(0, 1, 0)                                                  \
  STAGE_A_HALF(0, 0, 0)                                                  \
  STAGE_A_HALF(0, 1, 0)                                                  \
  STAGE_B_HALF(1, 0, 1)                                                  \
  STAGE_B_HALF(1, 1, 1)                                                  \
  asm volatile("s_waitcnt vmcnt(4)" ::: "memory");                       \
  __builtin_amdgcn_s_barrier();                                          \
  asm volatile("" ::: "memory");                                         \
  READ_BFR(0)                                                            \
  READ_QUAD(afrA, 0, 0)                                                  \
  _Pragma("unroll 2")                                                    \
  for (int t = 0; t < (NTv); ++t) {                                      \
    PH_PIPE(0, t, NTv, afrA, afrB)                                       \
    PH_PIPE(1, t, NTv, afrB, afrA)                                       \
    PH_PIPE(2, t, NTv, afrA, afrB)                                       \
    PH_PIPE(3, t, NTv, afrB, afrA)                                       \
  }

// GEMM1: h = gelu(x @ W1[e] + b1[e]); A xbf [cb][1024][512], B w1t [E][2048][512]
__global__ __launch_bounds__(512, 2) void k_gemm1(
    const __hip_bfloat16* __restrict__ xbf, const __hip_bfloat16* __restrict__ w1t,
    const float* __restrict__ b1, const int* __restrict__ idx, int b0, int nz,
    __hip_bfloat16* __restrict__ h) {
  constexpr int K = Cc;       // 512
  constexpr int N = HIDc;     // 2048
  constexpr int NT = K / 64;  // 8
  constexpr int NBX = N / 256, NBY = Tc / 256;  // 8, 4
  __shared__ short lds[2][2][256 * 64];  // 128 KB

  int nwg = NBX * NBY * nz;
  int cpx = nwg >> 3;
  int lg = (blockIdx.x & 7) * cpx + (blockIdx.x >> 3);
  int bx = lg % NBX, by = (lg / NBX) % NBY, bz = lg / (NBX * NBY);

  int e = idx[b0 + bz];
  int m0 = by * 256, n0 = bx * 256;
  const short* Ab = (const short*)xbf + ((size_t)bz * Tc + m0) * K;
  const short* Bb = (const short*)w1t + ((size_t)e * N + n0) * K;

  GEMM_PRELUDE(K)
  f4_t acc[8][4] = {};
  { KLOOP8(NT) }

  // epilogue: bias+gelu -> two-pass per-wave LDS transpose (stride 72)
  __syncthreads();
  short* chunk = &lds[0][0][0] + w * (64 * 72);  // 9216 B per wave
  const float* bias = b1 + (size_t)e * N;
  short* hb = (short*)(h + (size_t)bz * Tc * N);
  int cc2 = (l & 7) * 8;
#pragma unroll
  for (int p = 0; p < 2; ++p) {
#pragma unroll
    for (int fn = 0; fn < 4; ++fn) {
      float bv = bias[n0 + wc * 64 + fn * 16 + (l & 15)];
#pragma unroll
      for (int fm = 0; fm < 4; ++fm) {
        int rl = fm * 16 + ((l >> 4) << 2);
#pragma unroll
        for (int j = 0; j < 4; ++j) {
          float v = gelu_f(acc[p * 4 + fm][fn][j] + bv);
          chunk[(rl + j) * 72 + fn * 16 + (l & 15)] =
              (short)__bfloat16_as_ushort(__float2bfloat16(v));
        }
      }
    }
#pragma unroll
    for (int q = 0; q < 8; ++q) {
      int rr = q * 8 + (l >> 3);
      s8_t v = *(const s8_t*)(chunk + rr * 72 + cc2);
      *(s8_t*)(hb + (size_t)(m0 + wr * 128 + p * 64 + rr) * N + n0 + wc * 64 + cc2) = v;
    }
    // WAR fence: pass-1 LDS writes must not pass pass-0 reads
    asm volatile("s_waitcnt lgkmcnt(0)" ::: "memory");
  }
}

// GEMM2: y = h @ W2[e] + b2[e]; A h [cb][1024][2048], B w2t [E][512][2048]
__global__ __launch_bounds__(512, 2) void k_gemm2(
    const __hip_bfloat16* __restrict__ h, const __hip_bfloat16* __restrict__ w2t,
    const float* __restrict__ b2, const int* __restrict__ idx, int b0, int nz,
    float* __restrict__ out) {
  constexpr int K = HIDc;     // 2048
  constexpr int N = Cc;       // 512
  constexpr int NT = K / 64;  // 32
  constexpr int NBX = N / 256, NBY = Tc / 256;  // 2, 4
  __shared__ short lds[2][2][256 * 64];  // 128 KB

  int nwg = NBX * NBY * nz;  // 8*nz
  int cpx = nwg >> 3;
  int lg = (blockIdx.x & 7) * cpx + (blockIdx.x >> 3);
  int bx = lg % NBX, by = (lg / NBX) % NBY, bz = lg / (NBX * NBY);

  int e = idx[b0 + bz];
  int m0 = by * 256, n0 = bx * 256;
  const short* Ab = (const short*)h + ((size_t)bz * Tc + m0) * K;
  const short* Bb = (const short*)w2t + ((size_t)e * N + n0) * K;

  GEMM_PRELUDE(K)
  f4_t acc[8][4] = {};
  { KLOOP8(NT) }

  float* ob = out + (size_t)(b0 + bz) * Tc * N;
  const float* bias = b2 + (size_t)e * N;
#pragma unroll
  for (int fn = 0; fn < 4; ++fn) {
    int col = n0 + wc * 64 + fn * 16 + (l & 15);
    float bv = bias[col];
#pragma unroll
    for (int fm = 0; fm < 8; ++fm) {
      int rbase = m0 + wr * 128 + fm * 16 + ((l >> 4) << 2);
#pragma unroll
      for (int j = 0; j < 4; ++j) {
        ob[(size_t)(rbase + j) * N + col] = acc[fm][fn][j] + bv;
      }
    }
  }
}

extern "C" void kernel_launch(void* const* d_in, const int* in_sizes, int n_in,
                              void* d_out, int out_size, void* d_ws, size_t ws_size,
                              hipStream_t stream) {
  const float* x  = (const float*)d_in[0];
  const float* wg = (const float*)d_in[1];
  const float* W1 = (const float*)d_in[2];
  const float* b1 = (const float*)d_in[3];
  const float* W2 = (const float*)d_in[4];
  const float* b2 = (const float*)d_in[5];
  float* out = (float*)d_out;

  char* ws = (char*)d_ws;
  size_t off = 0;
  float* part = (float*)(ws + off); off += (size_t)Bc * 8 * Cc * 4;
  float* logits = (float*)(ws + off); off += (size_t)Bc * Ec * 4;
  int* idx = (int*)(ws + off); off += (size_t)Bc * 4;
  off = (off + 255) & ~(size_t)255;
  __hip_bfloat16* w1t = (__hip_bfloat16*)(ws + off); off += (size_t)Ec * HIDc * Cc * 2;
  __hip_bfloat16* w2t = (__hip_bfloat16*)(ws + off); off += (size_t)Ec * HIDc * Cc * 2;
  size_t dynoff = (off + 255) & ~(size_t)255;

  const size_t x_all = (size_t)Bc * Tc * Cc * 2;   // 64 MB
  const size_t x_per_b = (size_t)Tc * Cc * 2;      // 1 MB
  const size_t h_per_b = (size_t)Tc * HIDc * 2;    // 4 MB

  k_transpose_cvt<<<dim3(HIDc / 32, Cc / 32, Ec), 256, 0, stream>>>(W1, w1t, Cc, HIDc);
  k_transpose_cvt<<<dim3(Cc / 32, HIDc / 32, Ec), 256, 0, stream>>>(W2, w2t, HIDc, Cc);

  if (ws_size >= dynoff + x_all + h_per_b) {
    __hip_bfloat16* xbf = (__hip_bfloat16*)(ws + dynoff);
    __hip_bfloat16* hbf = (__hip_bfloat16*)(ws + dynoff + x_all);
    int cb = (int)((ws_size - dynoff - x_all) / h_per_b);
    if (cb > Bc) cb = Bc;

    k_prep<<<dim3(Bc, 8), 256, 0, stream>>>(x, (ushort*)xbf, part);
    k_xg_logits<<<dim3(Bc), 256, 0, stream>>>(part, wg, logits);
    k_gate<<<dim3(1), 256, 0, stream>>>(logits, idx, out + ((size_t)out_size - 1));

    for (int b0 = 0; b0 < Bc; b0 += cb) {
      int c = (Bc - b0) < cb ? (Bc - b0) : cb;
      const __hip_bfloat16* xc = xbf + (size_t)b0 * Tc * Cc;
      k_gemm1<<<dim3((HIDc / 256) * (Tc / 256) * c), 512, 0, stream>>>(
          xc, w1t, b1, idx, b0, c, hbf);
      k_gemm2<<<dim3((Cc / 256) * (Tc / 256) * c), 512, 0, stream>>>(
          hbf, w2t, b2, idx, b0, c, out);
    }
  } else {
    size_t avail = ws_size > dynoff ? ws_size - dynoff : 0;
    int cb = (int)(avail / (x_per_b + h_per_b));
    if (cb > Bc) cb = Bc;
    if (cb < 1) cb = 1;
    __hip_bfloat16* xbf = (__hip_bfloat16*)(ws + dynoff);
    __hip_bfloat16* hbf = (__hip_bfloat16*)(ws + dynoff + (size_t)cb * x_per_b);

    k_partial<<<dim3(Bc, 8), 256, 0, stream>>>(x, part);
    k_xg_logits<<<dim3(Bc), 256, 0, stream>>>(part, wg, logits);
    k_gate<<<dim3(1), 256, 0, stream>>>(logits, idx, out + ((size_t)out_size - 1));

    for (int b0 = 0; b0 < Bc; b0 += cb) {
      int c = (Bc - b0) < cb ? (Bc - b0) : cb;
      int n4 = c * (Tc * Cc / 4);
      k_cvt_x<<<dim3(1024), 256, 0, stream>>>(x + (size_t)b0 * Tc * Cc, (ushort*)xbf, n4);
      k_gemm1<<<dim3((HIDc / 256) * (Tc / 256) * c), 512, 0, stream>>>(
          xbf, w1t, b1, idx, b0, c, hbf);
      k_gemm2<<<dim3((Cc / 256) * (Tc / 256) * c), 512, 0, stream>>>(
          hbf, w2t, b2, idx, b0, c, out);
    }
  }
}

// Round 12
// 435.907 us; speedup vs baseline: 1.0190x; 1.0048x over previous
//
#include <hip/hip_runtime.h>
#include <hip/hip_bf16.h>
#include <math.h>

typedef __attribute__((ext_vector_type(4))) float f4_t;
typedef __attribute__((ext_vector_type(8))) short s8_t;

constexpr int Bc = 64;      // batches
constexpr int Tc = 1024;    // tokens per batch (H*W)
constexpr int Cc = 512;     // channels
constexpr int Ec = 5;       // experts
constexpr int HIDc = 2048;  // hidden

// async global->LDS, 16B per lane (linear LDS dest: wave-uniform base + lane*16)
__device__ __forceinline__ void async_copy16(const void* gsrc, void* ldst) {
  __builtin_amdgcn_global_load_lds(
      (const __attribute__((address_space(1))) unsigned int*)gsrc,
      (__attribute__((address_space(3))) unsigned int*)ldst, 16, 0, 0);
}

// tanh-form gelu, folded. |err vs exact erf-gelu| ~ 2e-4 (<< bf16 rounding).
__device__ __forceinline__ float gelu_f(float v) {
  float v2 = v * v;
  float z = v * (1.5957691216f + 0.0713548162f * v2);
  float e = __expf(z);
  float r = __frcp_rn(1.0f + e);
  return v - v * r;
}

// ---------------- gating / prep ----------------

__global__ void k_prep(const float* __restrict__ x, ushort* __restrict__ xbf,
                       float* __restrict__ part) {
  int b = blockIdx.x, p = blockIdx.y, tid = threadIdx.x;
  const float4* xp = (const float4*)(x + ((size_t)b * Tc + (size_t)p * 128) * Cc);
  ushort4* op = (ushort4*)(xbf + ((size_t)b * Tc + (size_t)p * 128) * Cc);
  int c4 = tid & 127, r0 = tid >> 7;
  float4 s = {0.f, 0.f, 0.f, 0.f};
  for (int r = r0; r < 128; r += 2) {
    float4 v = xp[(size_t)r * 128 + c4];
    s.x += v.x; s.y += v.y; s.z += v.z; s.w += v.w;
    union { __hip_bfloat16 h[4]; ushort4 u; } cv;
    cv.h[0] = __float2bfloat16(v.x);
    cv.h[1] = __float2bfloat16(v.y);
    cv.h[2] = __float2bfloat16(v.z);
    cv.h[3] = __float2bfloat16(v.w);
    op[(size_t)r * 128 + c4] = cv.u;
  }
  __shared__ float4 sh[128];
  if (r0) sh[c4] = s;
  __syncthreads();
  if (!r0) {
    float4 o = sh[c4];
    s.x += o.x; s.y += o.y; s.z += o.z; s.w += o.w;
    ((float4*)part)[(size_t)(b * 8 + p) * 128 + c4] = s;
  }
}

__global__ void k_partial(const float* __restrict__ x, float* __restrict__ part) {
  int b = blockIdx.x, p = blockIdx.y, tid = threadIdx.x;
  const float* xp = x + ((size_t)b * Tc + (size_t)p * 128) * Cc;
  float s0 = 0.f, s1 = 0.f;
  for (int t = 0; t < 128; ++t) {
    s0 += xp[(size_t)t * Cc + tid];
    s1 += xp[(size_t)t * Cc + tid + 256];
  }
  part[(size_t)(b * 8 + p) * Cc + tid] = s0;
  part[(size_t)(b * 8 + p) * Cc + tid + 256] = s1;
}

__global__ void k_cvt_x(const float* __restrict__ src, ushort* __restrict__ dst, int n4) {
  int i = blockIdx.x * blockDim.x + threadIdx.x;
  int stride = gridDim.x * blockDim.x;
  const float4* s4 = (const float4*)src;
  ushort4* d4 = (ushort4*)dst;
  for (; i < n4; i += stride) {
    float4 v = s4[i];
    union { __hip_bfloat16 h[4]; ushort4 u; } cv;
    cv.h[0] = __float2bfloat16(v.x);
    cv.h[1] = __float2bfloat16(v.y);
    cv.h[2] = __float2bfloat16(v.z);
    cv.h[3] = __float2bfloat16(v.w);
    d4[i] = cv.u;
  }
}

__global__ void k_xg_logits(const float* __restrict__ part, const float* __restrict__ wg,
                            float* __restrict__ logits) {
  __shared__ float xg[Cc];
  __shared__ float red[Ec][4];
  int b = blockIdx.x, tid = threadIdx.x;
  for (int c = tid; c < Cc; c += 256) {
    float s = 0.f;
#pragma unroll
    for (int p = 0; p < 8; ++p) s += part[(size_t)(b * 8 + p) * Cc + c];
    xg[c] = s * (1.0f / 1024.0f);
  }
  __syncthreads();
  float le[Ec] = {0.f, 0.f, 0.f, 0.f, 0.f};
  for (int c = tid; c < Cc; c += 256) {
    float v = xg[c];
#pragma unroll
    for (int e = 0; e < Ec; ++e) le[e] += v * wg[c * Ec + e];
  }
#pragma unroll
  for (int e = 0; e < Ec; ++e) {
    float v = le[e];
#pragma unroll
    for (int off = 32; off > 0; off >>= 1) v += __shfl_down(v, off);
    if ((tid & 63) == 0) red[e][tid >> 6] = v;
  }
  __syncthreads();
  if (tid < Ec) {
    float v = red[tid][0] + red[tid][1] + red[tid][2] + red[tid][3];
    v = fminf(fmaxf(v, -50.f), 50.f);
    logits[b * Ec + tid] = v;
  }
}

__global__ void k_gate(const float* __restrict__ logits, int* __restrict__ idx,
                       float* __restrict__ loss_out) {
  __shared__ int cnt[Ec];
  int tid = threadIdx.x;
  if (tid < Ec) cnt[tid] = 0;
  __syncthreads();
  if (tid < Bc) {
    const float* lb = logits + tid * Ec;
    int best = 0;
    float bv = lb[0];
#pragma unroll
    for (int e = 1; e < Ec; ++e) {
      float v = lb[e];
      if (v > bv) { bv = v; best = e; }
    }
    idx[tid] = best;
    atomicAdd(&cnt[best], 1);
  }
  __syncthreads();
  if (tid == 0) {
    const float mean = (float)Bc / (float)Ec;
    float var = 0.f;
#pragma unroll
    for (int e = 0; e < Ec; ++e) {
      float d = (float)cnt[e] - mean;
      var += d * d;
    }
    var *= (1.0f / (Ec - 1));
    float loss = 2.f * (var / (mean * mean + 1e-10f));
    loss = fminf(fmaxf(loss, 0.f), 1000.f);
    *loss_out = loss;
  }
}

__global__ void k_transpose_cvt(const float* __restrict__ src, __hip_bfloat16* __restrict__ dst,
                                int K, int N) {
  __shared__ float tile[32][33];
  int e = blockIdx.z;
  int kb = blockIdx.y * 32, nb = blockIdx.x * 32;
  const float* s = src + (size_t)e * K * N;
  __hip_bfloat16* d = dst + (size_t)e * K * N;
  int lx = threadIdx.x & 31, ly = threadIdx.x >> 5;
#pragma unroll
  for (int r = 0; r < 4; ++r) {
    int k = kb + ly + r * 8;
    tile[ly + r * 8][lx] = s[(size_t)k * N + nb + lx];
  }
  __syncthreads();
#pragma unroll
  for (int r = 0; r < 4; ++r) {
    int n = nb + ly + r * 8;
    d[(size_t)n * K + kb + lx] = __float2bfloat16(tile[lx][ly + r * 8]);
  }
}

// =====================================================================
// Race-free pipelined 4-phase schedule (R10 post-mortem fix), 256x256/
// BK=64/8-wave, dbuf LDS, T2 swizzle, T5 setprio, counted vmcnt.
// SAFETY RULE: LDS reads of freshly-staged data occur only AFTER a
// barrier that follows EVERY wave's draining vmcnt (per-wave vmcnt does
// not certify other waves' global_load_lds).  Hence: the q3 vmcnt(4)
// (outstanding=12 -> drains B(t+1)+A(t+1) exactly, leaves B(t+2) in
// flight) sits immediately before the q3 barrier; tile t+1's bfr/quad0
// reads happen at q0 AFTER that barrier.  Within-tile reads (quad1..3)
// are pipelined one phase ahead -- they target the CURRENT buffer,
// certified at the previous tile's q3.  Only q0's MFMA waits on reads.
// WAR: A(t+1)-stage vs old-buf quad3 read: 2 barriers apart; B(t+2)-
// stage (into cur-B at q2) vs cur-B bfr read (q0, consumed pre-q0-bar):
// 2 barriers apart.
// =====================================================================

#define GEMM_PRELUDE(KDIM)                                               \
  int tid = threadIdx.x, l = tid & 63, w = tid >> 6;                     \
  int wr = w >> 2, wc = w & 3;                                           \
  const short* gA[4];                                                    \
  const short* gB[4];                                                    \
  int loff[4];                                                           \
  _Pragma("unroll")                                                      \
  for (int i = 0; i < 4; ++i) {                                          \
    int sp = i * 512 + tid;                                              \
    int r = sp >> 3;                                                     \
    int c8 = ((sp & 7) ^ (r & 7)) << 3;                                  \
    gA[i] = Ab + (size_t)r * (KDIM) + c8;                                \
    gB[i] = Bb + (size_t)r * (KDIM) + c8;                                \
    loff[i] = sp * 16;                                                   \
  }                                                                      \
  int abase = (wr * 128 + (l & 15)) * 128;                               \
  int bbase = (wc * 64 + (l & 15)) * 128;                                \
  int s0 = (((l >> 4)) ^ (l & 7)) << 4;                                  \
  int s1 = (((l >> 4) + 4) ^ (l & 7)) << 4;

#define STAGE_A_HALF(buf, h, kt)                                         \
  {                                                                      \
    char* d_ = (char*)&lds[buf][0][0];                                   \
    int k0_ = (kt) * 64;                                                 \
    async_copy16(gA[2 * (h)] + k0_, d_ + loff[2 * (h)]);                 \
    async_copy16(gA[2 * (h) + 1] + k0_, d_ + loff[2 * (h) + 1]);         \
  }
#define STAGE_B_HALF(buf, h, kt)                                         \
  {                                                                      \
    char* d_ = (char*)&lds[buf][1][0];                                   \
    int k0_ = (kt) * 64;                                                 \
    async_copy16(gB[2 * (h)] + k0_, d_ + loff[2 * (h)]);                 \
    async_copy16(gB[2 * (h) + 1] + k0_, d_ + loff[2 * (h) + 1]);         \
  }

#define READ_QUAD(AFR, bufp, qq)                                         \
  {                                                                      \
    const char* Aq_ = (const char*)&lds[bufp][0][0];                     \
    AFR[0] = *(const s8_t*)(Aq_ + abase + ((qq) * 2 + 0) * 2048 + s0);   \
    AFR[1] = *(const s8_t*)(Aq_ + abase + ((qq) * 2 + 0) * 2048 + s1);   \
    AFR[2] = *(const s8_t*)(Aq_ + abase + ((qq) * 2 + 1) * 2048 + s0);   \
    AFR[3] = *(const s8_t*)(Aq_ + abase + ((qq) * 2 + 1) * 2048 + s1);   \
  }

#define READ_BFR(bufp)                                                   \
  {                                                                      \
    const char* Bq_ = (const char*)&lds[bufp][1][0];                     \
    _Pragma("unroll")                                                    \
    for (int fn = 0; fn < 4; ++fn) {                                     \
      bfr[fn * 2 + 0] = *(const s8_t*)(Bq_ + bbase + fn * 2048 + s0);    \
      bfr[fn * 2 + 1] = *(const s8_t*)(Bq_ + bbase + fn * 2048 + s1);    \
    }                                                                    \
  }

#define BAR()                          \
  __builtin_amdgcn_s_barrier();        \
  asm volatile("" ::: "memory")

#define MFMA_CLUSTER(q, AFR)                                                 \
  __builtin_amdgcn_s_setprio(1);                                             \
  _Pragma("unroll")                                                          \
  for (int kk = 0; kk < 2; ++kk)                                             \
    _Pragma("unroll")                                                        \
    for (int j = 0; j < 2; ++j)                                              \
      _Pragma("unroll")                                                      \
      for (int fn = 0; fn < 4; ++fn)                                         \
        acc[(q) * 2 + j][fn] = __builtin_amdgcn_mfma_f32_16x16x32_bf16(      \
            AFR[j * 2 + kk], bfr[fn * 2 + kk], acc[(q) * 2 + j][fn], 0, 0, 0); \
  __builtin_amdgcn_s_setprio(0);

// one K-tile t. cur = t&1.  afrA: quads 0,2; afrB: quads 1,3 (static).
#define TILE4(tt, NTv)                                                   \
  {                                                                      \
    const int cb_ = (tt) & 1;                                            \
    /* q0: entry barrier has certified buf cb_ */                        \
    if ((tt) + 1 < (NTv)) STAGE_A_HALF(cb_ ^ 1, 0, (tt) + 1)             \
    READ_BFR(cb_)                                                        \
    READ_QUAD(afrA, cb_, 0)                                              \
    MFMA_CLUSTER(0, afrA)                                                \
    READ_QUAD(afrB, cb_, 1)                                              \
    BAR();                                                               \
    /* q1 */                                                             \
    MFMA_CLUSTER(1, afrB)                                                \
    if ((tt) + 1 < (NTv)) STAGE_A_HALF(cb_ ^ 1, 1, (tt) + 1)             \
    READ_QUAD(afrA, cb_, 2)                                              \
    BAR();                                                               \
    /* q2 */                                                             \
    MFMA_CLUSTER(2, afrA)                                                \
    if ((tt) + 2 < (NTv)) STAGE_B_HALF(cb_, 0, (tt) + 2)                 \
    READ_QUAD(afrB, cb_, 3)                                              \
    BAR();                                                               \
    /* q3 */                                                             \
    MFMA_CLUSTER(3, afrB)                                                \
    if ((tt) + 2 < (NTv)) {                                              \
      STAGE_B_HALF(cb_, 1, (tt) + 2)                                     \
      asm volatile("s_waitcnt vmcnt(4)" ::: "memory");                   \
    } else if ((tt) + 1 < (NTv)) {                                       \
      asm volatile("s_waitcnt vmcnt(0)" ::: "memory");                   \
    }                                                                    \
    BAR();                                                               \
  }

#define KLOOP_P(NTv)                                                     \
  s8_t bfr[8], afrA[4], afrB[4];                                         \
  STAGE_B_HALF(0, 0, 0)                                                  \
  STAGE_B_HALF(0, 1, 0)                                                  \
  STAGE_A_HALF(0, 0, 0)                                                  \
  STAGE_A_HALF(0, 1, 0)                                                  \
  STAGE_B_HALF(1, 0, 1)                                                  \
  STAGE_B_HALF(1, 1, 1)                                                  \
  asm volatile("s_waitcnt vmcnt(4)" ::: "memory");                       \
  BAR();                                                                 \
  _Pragma("unroll 2")                                                    \
  for (int t = 0; t < (NTv); ++t) {                                      \
    TILE4(t, NTv)                                                        \
  }

// GEMM1: h = gelu(x @ W1[e] + b1[e]); A xbf [cb][1024][512], B w1t [E][2048][512]
__global__ __launch_bounds__(512, 2) void k_gemm1(
    const __hip_bfloat16* __restrict__ xbf, const __hip_bfloat16* __restrict__ w1t,
    const float* __restrict__ b1, const int* __restrict__ idx, int b0, int nz,
    __hip_bfloat16* __restrict__ h) {
  constexpr int K = Cc;       // 512
  constexpr int N = HIDc;     // 2048
  constexpr int NT = K / 64;  // 8
  constexpr int NBX = N / 256, NBY = Tc / 256;  // 8, 4
  __shared__ short lds[2][2][256 * 64];  // 128 KB

  int nwg = NBX * NBY * nz;
  int cpx = nwg >> 3;
  int lg = (blockIdx.x & 7) * cpx + (blockIdx.x >> 3);
  int bx = lg % NBX, by = (lg / NBX) % NBY, bz = lg / (NBX * NBY);

  int e = idx[b0 + bz];
  int m0 = by * 256, n0 = bx * 256;
  const short* Ab = (const short*)xbf + ((size_t)bz * Tc + m0) * K;
  const short* Bb = (const short*)w1t + ((size_t)e * N + n0) * K;

  GEMM_PRELUDE(K)
  f4_t acc[8][4] = {};
  { KLOOP_P(NT) }

  // epilogue: bias+gelu -> two-pass per-wave LDS transpose (stride 72)
  __syncthreads();
  short* chunk = &lds[0][0][0] + w * (64 * 72);  // 9216 B per wave
  const float* bias = b1 + (size_t)e * N;
  short* hb = (short*)(h + (size_t)bz * Tc * N);
  int cc2 = (l & 7) * 8;
#pragma unroll
  for (int p = 0; p < 2; ++p) {
#pragma unroll
    for (int fn = 0; fn < 4; ++fn) {
      float bv = bias[n0 + wc * 64 + fn * 16 + (l & 15)];
#pragma unroll
      for (int fm = 0; fm < 4; ++fm) {
        int rl = fm * 16 + ((l >> 4) << 2);
#pragma unroll
        for (int j = 0; j < 4; ++j) {
          float v = gelu_f(acc[p * 4 + fm][fn][j] + bv);
          chunk[(rl + j) * 72 + fn * 16 + (l & 15)] =
              (short)__bfloat16_as_ushort(__float2bfloat16(v));
        }
      }
    }
#pragma unroll
    for (int q = 0; q < 8; ++q) {
      int rr = q * 8 + (l >> 3);
      s8_t v = *(const s8_t*)(chunk + rr * 72 + cc2);
      *(s8_t*)(hb + (size_t)(m0 + wr * 128 + p * 64 + rr) * N + n0 + wc * 64 + cc2) = v;
    }
    // WAR fence: pass-1 LDS writes must not pass pass-0 reads
    asm volatile("s_waitcnt lgkmcnt(0)" ::: "memory");
  }
}

// GEMM2: y = h @ W2[e] + b2[e]; A h [cb][1024][2048], B w2t [E][512][2048]
__global__ __launch_bounds__(512, 2) void k_gemm2(
    const __hip_bfloat16* __restrict__ h, const __hip_bfloat16* __restrict__ w2t,
    const float* __restrict__ b2, const int* __restrict__ idx, int b0, int nz,
    float* __restrict__ out) {
  constexpr int K = HIDc;     // 2048
  constexpr int N = Cc;       // 512
  constexpr int NT = K / 64;  // 32
  constexpr int NBX = N / 256, NBY = Tc / 256;  // 2, 4
  __shared__ short lds[2][2][256 * 64];  // 128 KB

  int nwg = NBX * NBY * nz;  // 8*nz
  int cpx = nwg >> 3;
  int lg = (blockIdx.x & 7) * cpx + (blockIdx.x >> 3);
  int bx = lg % NBX, by = (lg / NBX) % NBY, bz = lg / (NBX * NBY);

  int e = idx[b0 + bz];
  int m0 = by * 256, n0 = bx * 256;
  const short* Ab = (const short*)h + ((size_t)bz * Tc + m0) * K;
  const short* Bb = (const short*)w2t + ((size_t)e * N + n0) * K;

  GEMM_PRELUDE(K)
  f4_t acc[8][4] = {};
  { KLOOP_P(NT) }

  float* ob = out + (size_t)(b0 + bz) * Tc * N;
  const float* bias = b2 + (size_t)e * N;
#pragma unroll
  for (int fn = 0; fn < 4; ++fn) {
    int col = n0 + wc * 64 + fn * 16 + (l & 15);
    float bv = bias[col];
#pragma unroll
    for (int fm = 0; fm < 8; ++fm) {
      int rbase = m0 + wr * 128 + fm * 16 + ((l >> 4) << 2);
#pragma unroll
      for (int j = 0; j < 4; ++j) {
        ob[(size_t)(rbase + j) * N + col] = acc[fm][fn][j] + bv;
      }
    }
  }
}

extern "C" void kernel_launch(void* const* d_in, const int* in_sizes, int n_in,
                              void* d_out, int out_size, void* d_ws, size_t ws_size,
                              hipStream_t stream) {
  const float* x  = (const float*)d_in[0];
  const float* wg = (const float*)d_in[1];
  const float* W1 = (const float*)d_in[2];
  const float* b1 = (const float*)d_in[3];
  const float* W2 = (const float*)d_in[4];
  const float* b2 = (const float*)d_in[5];
  float* out = (float*)d_out;

  char* ws = (char*)d_ws;
  size_t off = 0;
  float* part = (float*)(ws + off); off += (size_t)Bc * 8 * Cc * 4;
  float* logits = (float*)(ws + off); off += (size_t)Bc * Ec * 4;
  int* idx = (int*)(ws + off); off += (size_t)Bc * 4;
  off = (off + 255) & ~(size_t)255;
  __hip_bfloat16* w1t = (__hip_bfloat16*)(ws + off); off += (size_t)Ec * HIDc * Cc * 2;
  __hip_bfloat16* w2t = (__hip_bfloat16*)(ws + off); off += (size_t)Ec * HIDc * Cc * 2;
  size_t dynoff = (off + 255) & ~(size_t)255;

  const size_t x_all = (size_t)Bc * Tc * Cc * 2;   // 64 MB
  const size_t x_per_b = (size_t)Tc * Cc * 2;      // 1 MB
  const size_t h_per_b = (size_t)Tc * HIDc * 2;    // 4 MB

  k_transpose_cvt<<<dim3(HIDc / 32, Cc / 32, Ec), 256, 0, stream>>>(W1, w1t, Cc, HIDc);
  k_transpose_cvt<<<dim3(Cc / 32, HIDc / 32, Ec), 256, 0, stream>>>(W2, w2t, HIDc, Cc);

  if (ws_size >= dynoff + x_all + h_per_b) {
    __hip_bfloat16* xbf = (__hip_bfloat16*)(ws + dynoff);
    __hip_bfloat16* hbf = (__hip_bfloat16*)(ws + dynoff + x_all);
    int cb = (int)((ws_size - dynoff - x_all) / h_per_b);
    if (cb > Bc) cb = Bc;

    k_prep<<<dim3(Bc, 8), 256, 0, stream>>>(x, (ushort*)xbf, part);
    k_xg_logits<<<dim3(Bc), 256, 0, stream>>>(part, wg, logits);
    k_gate<<<dim3(1), 256, 0, stream>>>(logits, idx, out + ((size_t)out_size - 1));

    for (int b0 = 0; b0 < Bc; b0 += cb) {
      int c = (Bc - b0) < cb ? (Bc - b0) : cb;
      const __hip_bfloat16* xc = xbf + (size_t)b0 * Tc * Cc;
      k_gemm1<<<dim3((HIDc / 256) * (Tc / 256) * c), 512, 0, stream>>>(
          xc, w1t, b1, idx, b0, c, hbf);
      k_gemm2<<<dim3((Cc / 256) * (Tc / 256) * c), 512, 0, stream>>>(
          hbf, w2t, b2, idx, b0, c, out);
    }
  } else {
    size_t avail = ws_size > dynoff ? ws_size - dynoff : 0;
    int cb = (int)(avail / (x_per_b + h_per_b));
    if (cb > Bc) cb = Bc;
    if (cb < 1) cb = 1;
    __hip_bfloat16* xbf = (__hip_bfloat16*)(ws + dynoff);
    __hip_bfloat16* hbf = (__hip_bfloat16*)(ws + dynoff + (size_t)cb * x_per_b);

    k_partial<<<dim3(Bc, 8), 256, 0, stream>>>(x, part);
    k_xg_logits<<<dim3(Bc), 256, 0, stream>>>(part, wg, logits);
    k_gate<<<dim3(1), 256, 0, stream>>>(logits, idx, out + ((size_t)out_size - 1));

    for (int b0 = 0; b0 < Bc; b0 += cb) {
      int c = (Bc - b0) < cb ? (Bc - b0) : cb;
      int n4 = c * (Tc * Cc / 4);
      k_cvt_x<<<dim3(1024), 256, 0, stream>>>(x + (size_t)b0 * Tc * Cc, (ushort*)xbf, n4);
      k_gemm1<<<dim3((HIDc / 256) * (Tc / 256) * c), 512, 0, stream>>>(
          xbf, w1t, b1, idx, b0, c, hbf);
      k_gemm2<<<dim3((Cc / 256) * (Tc / 256) * c), 512, 0, stream>>>(
          hbf, w2t, b2, idx, b0, c, out);
    }
  }
}